// Round 8
// baseline (134.074 us; speedup 1.0000x reference)
//
#include <hip/hip_runtime.h>
#include <cfloat>

// Problem constants: M=N=64 grid, DIM=512, B=4096, SIGMA=32
#define DIMK 512
#define MN   4096
#define BATCH 4096
#define NGRP 1024   // 4-column groups per row

typedef _Float16 half8_t __attribute__((ext_vector_type(8)));
typedef _Float16 half4_t __attribute__((ext_vector_type(4)));
typedef float f32x4 __attribute__((ext_vector_type(4)));

// async global->LDS, 16B per lane; LDS dest is wave-uniform base + lane*16
#define GLD16(gp, lp) __builtin_amdgcn_global_load_lds( \
    (const __attribute__((address_space(1))) void*)(gp), \
    (__attribute__((address_space(3))) void*)(lp), 16, 0, 0)

// ---------------------------------------------------------------------------
// Convert: X,W fp32 -> f16 RTN + exact fp32 row norms. (unchanged)
// ---------------------------------------------------------------------------
__global__ __launch_bounds__(256) void convert_kernel(
        const float* __restrict__ X, const float* __restrict__ W,
        _Float16* __restrict__ Xh, _Float16* __restrict__ Wh,
        float* __restrict__ w2, float* __restrict__ xnorm) {
    const int blk  = blockIdx.x;
    const int t    = threadIdx.x;
    const bool isW = blk >= 1024;
    const float* src = isW ? W : X;
    _Float16* dst  = isW ? Wh : Xh;
    const int rblk = isW ? blk - 1024 : blk;
    const size_t idx = (size_t)rblk * 2048 + (size_t)t * 8;

    float4 v0 = *(const float4*)(src + idx);
    float4 v1 = *(const float4*)(src + idx + 4);
    float v[8] = {v0.x, v0.y, v0.z, v0.w, v1.x, v1.y, v1.z, v1.w};
    half8_t hv;
    float s = 0.f;
#pragma unroll
    for (int e = 0; e < 8; e++) {
        s += v[e] * v[e];
        hv[e] = (_Float16)v[e];
    }
    *(half8_t*)(dst + idx) = hv;
#pragma unroll
    for (int o = 32; o > 0; o >>= 1) s += __shfl_down(s, o);
    if ((t & 63) == 0) {
        int row = rblk * 4 + (t >> 6);
        if (isW) w2[row] = s;
        else     xnorm[row] = __fsqrt_rn(s);
    }
}

// ---------------------------------------------------------------------------
// Score GEMM v8: TLP push. Wave-tile 64x32 (acc 4x2 f32x4 = 32 VGPR,
// ~75-85 total) -> 5 waves/SIMD fit -> __launch_bounds__(256,5) =
// 5 blocks/CU, 20 waves/CU (+25% vs R7's VGPR-capped 16). Block tile
// 128x64 (4 waves: 2m x 2n-halves), BK=32, double-buffered 24 KiB LDS.
// Staging/addressing identical to R6/R7 (coalesced 16-lines/instr,
// both-sides XOR chunk swizzle; the reduction x(row)=(r16>>1)&3 holds for
// all new row bases, all == 0 mod the XOR period). 2-phase schedule as R7:
// {STAGE next -> ds_read cur -> lgkmcnt(0) -> 8 MFMA -> vmcnt(0) ->
// s_barrier}. K-order and C-fragment mapping identical to all prior
// rounds -> bit-identical group-mins -> screen margins unchanged.
// ---------------------------------------------------------------------------
__global__ __launch_bounds__(256, 5) void score_kernel(
        const _Float16* __restrict__ Xh, const _Float16* __restrict__ Wh,
        const float* __restrict__ w2, _Float16* __restrict__ Gm) {
    // buffer = [A 4096 f16 (128 rows x 32)][B 2048 (64 rows x 32)] = 12 KiB
    __shared__ __align__(16) _Float16 lds[2][6144];

    const int t    = threadIdx.x;
    const int lane = t & 63;
    const int w    = t >> 6;        // wave 0..3
    const int wm   = w >> 1;        // m-half (0..1) -> 64 rows
    const int wn   = w & 1;         // n-half (0..1) -> 32 cols

    // bijective XCD swizzle: 2048 blocks, 8 XCDs x 256; per XCD an
    // 8(bm) x 32(bn) rect -> working set A 1MB + B 2MB = 3MB < 4MB L2.
    const int id  = blockIdx.y * 32 + blockIdx.x;   // gridDim (32,64)
    const int xcd = id & 7;
    const int li  = id >> 3;                        // 0..255
    const int bm  = (xcd >> 1) * 8 + (li >> 5);     // 0..31 (128-row tiles)
    const int bn  = (xcd & 1) * 32 + (li & 31);     // 0..63 (64-col tiles)
    const int m0  = bm * 128;
    const int n0  = bn * 64;

    const _Float16* gA = Xh + (size_t)m0 * DIMK;
    const _Float16* gB = Wh + (size_t)n0 * DIMK;

    // staging source (per-lane, f16 units): row-in-group = lane>>2,
    // source chunk = (lane&3) ^ x(row), x(row) = (lane>>3)&3.
    // Lanes 0-3 read contiguous 64B of one row -> 16 cache lines/instr.
    const int soff = (lane >> 2) * DIMK + (((lane & 3) ^ ((lane >> 3) & 3)) * 8);

    // STG(reg, rb, kt, sl): stage rows [rb, rb+16) of region reg (0=A,1=B),
    // k-slice kt, into buffer sl. LDS dest wave-uniform (HW adds lane*16B).
#define STG(reg, rb, kt, sl) GLD16( \
    ((reg) ? gB : gA) + (size_t)(rb) * DIMK + (kt) * 32 + soff, \
    &lds[sl][(reg) * 4096 + (rb) * 32])

    // fragment ds_read addr: chunk = kg ^ ((r16>>1)&3)
    const int r16 = lane & 15;
    const int kg  = lane >> 4;
    const int xx  = (r16 >> 1) & 3;
    const int aoff =        wm * 2048 + r16 * 32 + ((kg ^ xx) * 8);
    const int boff = 4096 + wn * 1024 + r16 * 32 + ((kg ^ xx) * 8);

#define LDA(sl, rg) (*(const half8_t*)(&lds[sl][aoff + (rg) * 512]))
#define LDB(sl, rg) (*(const half8_t*)(&lds[sl][boff + (rg) * 512]))

    f32x4 acc[4][2];
#pragma unroll
    for (int i = 0; i < 4; i++)
#pragma unroll
        for (int j = 0; j < 2; j++) acc[i][j] = (f32x4){0.f, 0.f, 0.f, 0.f};

    // per-wave staging ownership: A rows w*32..+32 (2 instr), B rows w*16..+16
    const int wa = w * 32;
    const int wb = w * 16;

    // prologue: stage tile 0 into buffer 0, drain, sync
    STG(0, wa,      0, 0);
    STG(0, wa + 16, 0, 0);
    STG(1, wb,      0, 0);
    asm volatile("s_waitcnt vmcnt(0)" ::: "memory");
    __builtin_amdgcn_s_barrier();

#pragma unroll
    for (int kt = 0; kt < 16; ++kt) {
        const int sl = kt & 1;
        const int nx = sl ^ 1;

        // issue next tile's 3 loads into the other buffer (safe: all waves
        // finished reading it before the barrier that ended iter kt-1)
        if (kt < 15) {
            STG(0, wa,      kt + 1, nx);
            STG(0, wa + 16, kt + 1, nx);
            STG(1, wb,      kt + 1, nx);
        }

        half8_t a0 = LDA(sl, 0), a1 = LDA(sl, 1);
        half8_t a2 = LDA(sl, 2), a3 = LDA(sl, 3);
        half8_t b0 = LDB(sl, 0), b1 = LDB(sl, 1);

        asm volatile("s_waitcnt lgkmcnt(0)" ::: "memory");
        __builtin_amdgcn_sched_barrier(0);
        __builtin_amdgcn_s_setprio(1);
#pragma unroll
        for (int i = 0; i < 4; i++) {
            half8_t av = (i == 0) ? a0 : (i == 1) ? a1 : (i == 2) ? a2 : a3;
            acc[i][0] = __builtin_amdgcn_mfma_f32_16x16x32_f16(av, b0, acc[i][0], 0, 0, 0);
            acc[i][1] = __builtin_amdgcn_mfma_f32_16x16x32_f16(av, b1, acc[i][1], 0, 0, 0);
        }
        __builtin_amdgcn_s_setprio(0);

        // end-gate: next tile landed AND all waves' reads of buffer sl done
        asm volatile("s_waitcnt vmcnt(0)" ::: "memory");
        __builtin_amdgcn_sched_barrier(0);
        __builtin_amdgcn_s_barrier();
    }

    // ---- 4-col group mins -> f16, packed 1024/row (verified layout).
    // D layout: col=lane&15, row=(lane>>4)*4+v ----
    const int q   = lane >> 4;
    const int cl  = lane & 15;
    const int gb  = (n0 >> 2) + wn * 8;
    float w2v[2];
#pragma unroll
    for (int j = 0; j < 2; j++) w2v[j] = w2[n0 + wn * 32 + j * 16 + cl];
#pragma unroll
    for (int i = 0; i < 4; i++)
#pragma unroll
        for (int v = 0; v < 4; v++) {
            const int row = m0 + wm * 64 + i * 16 + q * 4 + v;
            _Float16* grow = Gm + (size_t)row * 1024 + gb;
#pragma unroll
            for (int j = 0; j < 2; j++) {
                float s = w2v[j] - 2.0f * acc[i][j][v];
                s = fminf(s, __shfl_xor(s, 1));
                s = fminf(s, __shfl_xor(s, 2));
                if ((cl & 3) == 0) grow[j * 4 + (cl >> 2)] = (_Float16)s;
            }
        }
}

// ---------------------------------------------------------------------------
// Fused epilogue: f16 group-min screen + 4-col-concurrent exact fp32 rescore
// (16 lanes/col, coalesced float4 W reads, order-preserving u64 min key)
// + uniform merge + separable Gaussian row write. (unchanged)
// ---------------------------------------------------------------------------
__global__ __launch_bounds__(256) void epilogue_kernel(
        const float* __restrict__ w2, const float* __restrict__ xnorm,
        const float* __restrict__ X, const float* __restrict__ W,
        const _Float16* __restrict__ gm,
        const int* __restrict__ decay_p, const int* __restrict__ it_p,
        float* __restrict__ out) {
    __shared__ float xs[512];
    __shared__ int   list[NGRP];
    __shared__ int   cnt;
    __shared__ float wmin[4];
    __shared__ unsigned long long wkey[4];
    __shared__ float tab[128];
    const int row  = blockIdx.x;
    const int t    = threadIdx.x;
    const int lane = t & 63;
    const int w    = t >> 6;

    {
        float2 xv = *(const float2*)(X + (size_t)row * DIMK + t * 2);
        xs[2 * t]     = xv.x;
        xs[2 * t + 1] = xv.y;
    }
    if (t == 0) cnt = 0;

    // f16 group-mins: 4 per thread (8B coalesced), packed 2KB/row
    half4_t gmh = *((const half4_t*)(gm + (size_t)row * 1024) + t);
    float gme[4] = {(float)gmh[0], (float)gmh[1], (float)gmh[2], (float)gmh[3]};
    float g = fminf(fminf(gme[0], gme[1]), fminf(gme[2], gme[3]));
#pragma unroll
    for (int mask = 1; mask <= 32; mask <<= 1)
        g = fminf(g, __shfl_xor(g, mask));
    if (lane == 0) wmin[w] = g;
    __syncthreads();
    const float gmin = fminf(fminf(wmin[0], wmin[1]), fminf(wmin[2], wmin[3]));
    const float tau  = gmin + 2.0f * (0.0222f * xnorm[row] + 0.25f);

#pragma unroll
    for (int e = 0; e < 4; e++)
        if (gme[e] <= tau) list[atomicAdd(&cnt, 1)] = t * 4 + e;
    __syncthreads();
    const int total = cnt;            // >= 1 always (gmin's group qualifies)

    // preload this lane's x-slice: float4 elems e*16 + s16, e = 0..7
    const int s16 = lane & 15;
    const int cg  = lane >> 4;        // column-in-group this lane serves
    float4 xq[8];
#pragma unroll
    for (int e = 0; e < 8; e++) xq[e] = ((const float4*)xs)[e * 16 + s16];

    unsigned long long mkey = ~0ULL;
    for (int idx = w; idx < total; idx += 4) {
        const int col = list[idx] * 4 + cg;
        const float4* wr = (const float4*)(W + (size_t)col * DIMK);
        float p = 0.f;
#pragma unroll
        for (int e = 0; e < 8; e++) {
            float4 wv = wr[e * 16 + s16];   // 16 lanes x 16B contiguous / col
            p += xq[e].x * wv.x + xq[e].y * wv.y
               + xq[e].z * wv.z + xq[e].w * wv.w;
        }
        p += __shfl_xor(p, 1); p += __shfl_xor(p, 2);
        p += __shfl_xor(p, 4); p += __shfl_xor(p, 8);
        const float s = w2[col] - 2.0f * p;
        unsigned int b = __float_as_uint(s);
        unsigned int u = (b & 0x80000000u) ? ~b : (b | 0x80000000u);
        unsigned long long key = ((unsigned long long)u << 32) | (unsigned int)col;
        mkey = key < mkey ? key : mkey;
    }
    {   // fold the 4 column-sets (lane bits 4,5)
        unsigned long long o;
        o = __shfl_xor(mkey, 16); mkey = o < mkey ? o : mkey;
        o = __shfl_xor(mkey, 32); mkey = o < mkey ? o : mkey;
    }
    if (lane == 0) wkey[w] = mkey;
    __syncthreads();
    // uniform merge: every thread computes the same winner
    unsigned long long k = wkey[0];
#pragma unroll
    for (int i = 1; i < 4; i++) k = wkey[i] < k ? wkey[i] : k;
    const int sbi = (int)(k & 0xffffffffu);

    // separable Gaussian tables + row write
    const float lr  = __expf(-(float)(*it_p) / (float)(*decay_p));
    const float so  = 32.0f * lr;          // SIGMA = 32
    const float inv = 1.0f / (so * so);
    const int rr = sbi >> 6, cc = sbi & 63;
    if (t < 64) {
        float d = (float)(t - rr);
        tab[t] = __expf(-d * d * inv);
    } else if (t < 128) {
        float d = (float)(t - 64 - cc);
        tab[t] = __expf(-d * d * inv);
    }
    __syncthreads();
    const float* er = tab;
    const float* ec = tab + 64;
    f32x4* orow = (f32x4*)(out + (size_t)row * 4096);
#pragma unroll
    for (int qq = 0; qq < 4; qq++) {
        int f  = qq * 256 + t;
        int i  = f >> 4;
        int j0 = (f & 15) * 4;
        float e = er[i];
        f32x4 o = {e * ec[j0], e * ec[j0 + 1], e * ec[j0 + 2], e * ec[j0 + 3]};
        __builtin_nontemporal_store(o, orow + f);
    }
}

// ---------------------------------------------------------------------------
extern "C" void kernel_launch(void* const* d_in, const int* in_sizes, int n_in,
                              void* d_out, int out_size, void* d_ws, size_t ws_size,
                              hipStream_t stream) {
    const float* X       = (const float*)d_in[0];   // [4096,512]
    const float* W       = (const float*)d_in[1];   // [4096,512]
    const int*   decay_p = (const int*)d_in[3];
    const int*   it_p    = (const int*)d_in[4];
    float* out = (float*)d_out;

    // ws: Xh 4MB | Wh 4MB | w2 16KB | xnorm 16KB | gmins 8MB
    _Float16* Xh = (_Float16*)d_ws;
    _Float16* Wh = Xh + (size_t)BATCH * DIMK;
    float*    w2 = (float*)(Wh + (size_t)MN * DIMK);
    float*    xn = w2 + MN;
    _Float16* gmv = (_Float16*)(xn + BATCH);

    convert_kernel<<<2048, 256, 0, stream>>>(X, W, Xh, Wh, w2, xn);
    score_kernel<<<dim3(32, 64), 256, 0, stream>>>(Xh, Wh, w2, gmv);
    epilogue_kernel<<<BATCH, 256, 0, stream>>>(w2, xn, X, W, gmv, decay_p, it_p, out);
}

// Round 9
// 129.518 us; speedup vs baseline: 1.0352x; 1.0352x over previous
//
#include <hip/hip_runtime.h>
#include <cfloat>

// Problem constants: M=N=64 grid, DIM=512, B=4096, SIGMA=32
#define DIMK 512
#define MN   4096
#define BATCH 4096
#define NGRP 1024   // 4-column groups per row

typedef _Float16 half8_t __attribute__((ext_vector_type(8)));
typedef _Float16 half4_t __attribute__((ext_vector_type(4)));
typedef float f32x4 __attribute__((ext_vector_type(4)));

// async global->LDS, 16B per lane; LDS dest is wave-uniform base + lane*16
#define GLD16(gp, lp) __builtin_amdgcn_global_load_lds( \
    (const __attribute__((address_space(1))) void*)(gp), \
    (__attribute__((address_space(3))) void*)(lp), 16, 0, 0)

// ---------------------------------------------------------------------------
// Convert: X,W fp32 -> f16 RTN + exact fp32 row norms. (unchanged)
// ---------------------------------------------------------------------------
__global__ __launch_bounds__(256) void convert_kernel(
        const float* __restrict__ X, const float* __restrict__ W,
        _Float16* __restrict__ Xh, _Float16* __restrict__ Wh,
        float* __restrict__ w2, float* __restrict__ xnorm) {
    const int blk  = blockIdx.x;
    const int t    = threadIdx.x;
    const bool isW = blk >= 1024;
    const float* src = isW ? W : X;
    _Float16* dst  = isW ? Wh : Xh;
    const int rblk = isW ? blk - 1024 : blk;
    const size_t idx = (size_t)rblk * 2048 + (size_t)t * 8;

    float4 v0 = *(const float4*)(src + idx);
    float4 v1 = *(const float4*)(src + idx + 4);
    float v[8] = {v0.x, v0.y, v0.z, v0.w, v1.x, v1.y, v1.z, v1.w};
    half8_t hv;
    float s = 0.f;
#pragma unroll
    for (int e = 0; e < 8; e++) {
        s += v[e] * v[e];
        hv[e] = (_Float16)v[e];
    }
    *(half8_t*)(dst + idx) = hv;
#pragma unroll
    for (int o = 32; o > 0; o >>= 1) s += __shfl_down(s, o);
    if ((t & 63) == 0) {
        int row = rblk * 4 + (t >> 6);
        if (isW) w2[row] = s;
        else     xnorm[row] = __fsqrt_rn(s);
    }
}

// ---------------------------------------------------------------------------
// Score GEMM v7 (measured session-best, re-locked): coalesced+swizzled
// staging, 128x128 tile, 4 waves, BK=32, double-buffered 32 KiB LDS,
// __launch_bounds__(256,4) -> 4 blocks/CU (16 waves/CU). 2-phase schedule:
// {STAGE next -> ds_read cur -> lgkmcnt(0) -> 16 MFMA -> vmcnt(0) ->
// s_barrier}. The per-block vmcnt(0) drain is hidden by the other 3
// co-resident blocks (m114 overlap) — the session's two confirmed
// mechanisms (coalesced staging −8 us, 4-blk co-residency −7 us) combined.
// R8 falsified TLP>16 waves/CU (overhead grows faster than hiding).
// Fragment reads, K-order, and tail bit-identical -> identical group-mins.
// ---------------------------------------------------------------------------
__global__ __launch_bounds__(256, 4) void score_kernel(
        const _Float16* __restrict__ Xh, const _Float16* __restrict__ Wh,
        const float* __restrict__ w2, _Float16* __restrict__ Gm) {
    // slot = [A 4096 f16 (128 rows x 32)][B 4096] = 16 KiB; double-buffer.
    __shared__ __align__(16) _Float16 lds[2][8192];

    const int t    = threadIdx.x;
    const int lane = t & 63;
    const int w    = t >> 6;        // wave 0..3
    const int wm   = w >> 1;        // m-half (0..1) -> 64 rows
    const int wn   = w & 1;         // n-half (0..1) -> 64 cols

    // bijective XCD swizzle: 1024 blocks, 8 XCDs x 128; per XCD an
    // 8(bm) x 16(bn) rect -> working set A 1MB + B 2MB = 3MB < 4MB L2.
    const int id  = blockIdx.y * 32 + blockIdx.x;   // gridDim (32,32)
    const int xcd = id & 7;
    const int li  = id >> 3;                        // 0..127
    const int bm  = (xcd >> 1) * 8 + (li >> 4);     // 0..31
    const int bn  = (xcd & 1) * 16 + (li & 15);     // 0..31
    const int m0  = bm * 128;
    const int n0  = bn * 128;

    const _Float16* gA = Xh + (size_t)m0 * DIMK;
    const _Float16* gB = Wh + (size_t)n0 * DIMK;

    // staging source (per-lane, f16 units): row-in-group = lane>>2,
    // source chunk = (lane&3) ^ x(row), x(row) = (lane>>3)&3.
    // Lanes 0-3 read contiguous 64B of one row (permuted 16B chunks)
    // -> 16 cache lines per gld_lds instead of 64.
    const int soff = (lane >> 2) * DIMK + (((lane & 3) ^ ((lane >> 3) & 3)) * 8);

    // STG(reg, rb, kt, sl): stage rows [rb, rb+16) of region reg, k-slice kt,
    // into buffer sl. LDS dest is wave-uniform (HW adds lane*16B).
#define STG(reg, rb, kt, sl) GLD16( \
    ((reg) ? gB : gA) + (size_t)(rb) * DIMK + (kt) * 32 + soff, \
    &lds[sl][(reg) * 4096 + (rb) * 32])

    // fragment ds_read addr: row = half*64 + rg*16 + r16, chunk = kg ^ x(row);
    // x(row) reduces to (r16>>1)&3.
    const int r16 = lane & 15;
    const int kg  = lane >> 4;
    const int xx  = (r16 >> 1) & 3;
    const int aoff =        wm * 2048 + r16 * 32 + ((kg ^ xx) * 8);
    const int boff = 4096 + wn * 2048 + r16 * 32 + ((kg ^ xx) * 8);

#define LDA(sl, rg) (*(const half8_t*)(&lds[sl][aoff + (rg) * 512]))
#define LDB(sl, rg) (*(const half8_t*)(&lds[sl][boff + (rg) * 512]))

    f32x4 acc[4][4];
#pragma unroll
    for (int i = 0; i < 4; i++)
#pragma unroll
        for (int j = 0; j < 4; j++) acc[i][j] = (f32x4){0.f, 0.f, 0.f, 0.f};

    const int w32 = w * 32;
    // prologue: stage tile 0 into buffer 0, drain, sync
    STG(0, w32,      0, 0);
    STG(0, w32 + 16, 0, 0);
    STG(1, w32,      0, 0);
    STG(1, w32 + 16, 0, 0);
    asm volatile("s_waitcnt vmcnt(0)" ::: "memory");
    __builtin_amdgcn_s_barrier();

#pragma unroll
    for (int kt = 0; kt < 16; ++kt) {
        const int sl = kt & 1;
        const int nx = sl ^ 1;

        // issue next tile's 4 loads into the other buffer (safe: all waves
        // finished reading it before the barrier that ended iter kt-1)
        if (kt < 15) {
            STG(0, w32,      kt + 1, nx);
            STG(0, w32 + 16, kt + 1, nx);
            STG(1, w32,      kt + 1, nx);
            STG(1, w32 + 16, kt + 1, nx);
        }

        half8_t a0 = LDA(sl, 0), a1 = LDA(sl, 1);
        half8_t a2 = LDA(sl, 2), a3 = LDA(sl, 3);
        half8_t b0 = LDB(sl, 0), b1 = LDB(sl, 1);
        half8_t b2 = LDB(sl, 2), b3 = LDB(sl, 3);

        asm volatile("s_waitcnt lgkmcnt(0)" ::: "memory");
        __builtin_amdgcn_sched_barrier(0);
        __builtin_amdgcn_s_setprio(1);
#pragma unroll
        for (int i = 0; i < 4; i++) {
            half8_t av = (i == 0) ? a0 : (i == 1) ? a1 : (i == 2) ? a2 : a3;
            acc[i][0] = __builtin_amdgcn_mfma_f32_16x16x32_f16(av, b0, acc[i][0], 0, 0, 0);
            acc[i][1] = __builtin_amdgcn_mfma_f32_16x16x32_f16(av, b1, acc[i][1], 0, 0, 0);
            acc[i][2] = __builtin_amdgcn_mfma_f32_16x16x32_f16(av, b2, acc[i][2], 0, 0, 0);
            acc[i][3] = __builtin_amdgcn_mfma_f32_16x16x32_f16(av, b3, acc[i][3], 0, 0, 0);
        }
        __builtin_amdgcn_s_setprio(0);

        // end-gate: next tile landed (own 4 loads drained) AND all waves'
        // reads of buffer sl complete -> iter kt+1 may stage into sl.
        asm volatile("s_waitcnt vmcnt(0)" ::: "memory");
        __builtin_amdgcn_sched_barrier(0);
        __builtin_amdgcn_s_barrier();
    }

    // ---- 4-col group mins -> f16, packed 1024/row (verified layout).
    // D layout: col=lane&15, row=(lane>>4)*4+v ----
    const int q   = lane >> 4;
    const int cl  = lane & 15;
    const int gb  = (n0 >> 2) + wn * 16;
    float w2v[4];
#pragma unroll
    for (int j = 0; j < 4; j++) w2v[j] = w2[n0 + wn * 64 + j * 16 + cl];
#pragma unroll
    for (int i = 0; i < 4; i++)
#pragma unroll
        for (int v = 0; v < 4; v++) {
            const int row = m0 + wm * 64 + i * 16 + q * 4 + v;
            _Float16* grow = Gm + (size_t)row * 1024 + gb;
#pragma unroll
            for (int j = 0; j < 4; j++) {
                float s = w2v[j] - 2.0f * acc[i][j][v];
                s = fminf(s, __shfl_xor(s, 1));
                s = fminf(s, __shfl_xor(s, 2));
                if ((cl & 3) == 0) grow[j * 4 + (cl >> 2)] = (_Float16)s;
            }
        }
}

// ---------------------------------------------------------------------------
// Fused epilogue: f16 group-min screen + 4-col-concurrent exact fp32 rescore
// (16 lanes/col, coalesced float4 W reads, order-preserving u64 min key)
// + uniform merge + separable Gaussian row write. (unchanged)
// ---------------------------------------------------------------------------
__global__ __launch_bounds__(256) void epilogue_kernel(
        const float* __restrict__ w2, const float* __restrict__ xnorm,
        const float* __restrict__ X, const float* __restrict__ W,
        const _Float16* __restrict__ gm,
        const int* __restrict__ decay_p, const int* __restrict__ it_p,
        float* __restrict__ out) {
    __shared__ float xs[512];
    __shared__ int   list[NGRP];
    __shared__ int   cnt;
    __shared__ float wmin[4];
    __shared__ unsigned long long wkey[4];
    __shared__ float tab[128];
    const int row  = blockIdx.x;
    const int t    = threadIdx.x;
    const int lane = t & 63;
    const int w    = t >> 6;

    {
        float2 xv = *(const float2*)(X + (size_t)row * DIMK + t * 2);
        xs[2 * t]     = xv.x;
        xs[2 * t + 1] = xv.y;
    }
    if (t == 0) cnt = 0;

    // f16 group-mins: 4 per thread (8B coalesced), packed 2KB/row
    half4_t gmh = *((const half4_t*)(gm + (size_t)row * 1024) + t);
    float gme[4] = {(float)gmh[0], (float)gmh[1], (float)gmh[2], (float)gmh[3]};
    float g = fminf(fminf(gme[0], gme[1]), fminf(gme[2], gme[3]));
#pragma unroll
    for (int mask = 1; mask <= 32; mask <<= 1)
        g = fminf(g, __shfl_xor(g, mask));
    if (lane == 0) wmin[w] = g;
    __syncthreads();
    const float gmin = fminf(fminf(wmin[0], wmin[1]), fminf(wmin[2], wmin[3]));
    const float tau  = gmin + 2.0f * (0.0222f * xnorm[row] + 0.25f);

#pragma unroll
    for (int e = 0; e < 4; e++)
        if (gme[e] <= tau) list[atomicAdd(&cnt, 1)] = t * 4 + e;
    __syncthreads();
    const int total = cnt;            // >= 1 always (gmin's group qualifies)

    // preload this lane's x-slice: float4 elems e*16 + s16, e = 0..7
    const int s16 = lane & 15;
    const int cg  = lane >> 4;        // column-in-group this lane serves
    float4 xq[8];
#pragma unroll
    for (int e = 0; e < 8; e++) xq[e] = ((const float4*)xs)[e * 16 + s16];

    unsigned long long mkey = ~0ULL;
    for (int idx = w; idx < total; idx += 4) {
        const int col = list[idx] * 4 + cg;
        const float4* wr = (const float4*)(W + (size_t)col * DIMK);
        float p = 0.f;
#pragma unroll
        for (int e = 0; e < 8; e++) {
            float4 wv = wr[e * 16 + s16];   // 16 lanes x 16B contiguous / col
            p += xq[e].x * wv.x + xq[e].y * wv.y
               + xq[e].z * wv.z + xq[e].w * wv.w;
        }
        p += __shfl_xor(p, 1); p += __shfl_xor(p, 2);
        p += __shfl_xor(p, 4); p += __shfl_xor(p, 8);
        const float s = w2[col] - 2.0f * p;
        unsigned int b = __float_as_uint(s);
        unsigned int u = (b & 0x80000000u) ? ~b : (b | 0x80000000u);
        unsigned long long key = ((unsigned long long)u << 32) | (unsigned int)col;
        mkey = key < mkey ? key : mkey;
    }
    {   // fold the 4 column-sets (lane bits 4,5)
        unsigned long long o;
        o = __shfl_xor(mkey, 16); mkey = o < mkey ? o : mkey;
        o = __shfl_xor(mkey, 32); mkey = o < mkey ? o : mkey;
    }
    if (lane == 0) wkey[w] = mkey;
    __syncthreads();
    // uniform merge: every thread computes the same winner
    unsigned long long k = wkey[0];
#pragma unroll
    for (int i = 1; i < 4; i++) k = wkey[i] < k ? wkey[i] : k;
    const int sbi = (int)(k & 0xffffffffu);

    // separable Gaussian tables + row write
    const float lr  = __expf(-(float)(*it_p) / (float)(*decay_p));
    const float so  = 32.0f * lr;          // SIGMA = 32
    const float inv = 1.0f / (so * so);
    const int rr = sbi >> 6, cc = sbi & 63;
    if (t < 64) {
        float d = (float)(t - rr);
        tab[t] = __expf(-d * d * inv);
    } else if (t < 128) {
        float d = (float)(t - 64 - cc);
        tab[t] = __expf(-d * d * inv);
    }
    __syncthreads();
    const float* er = tab;
    const float* ec = tab + 64;
    f32x4* orow = (f32x4*)(out + (size_t)row * 4096);
#pragma unroll
    for (int qq = 0; qq < 4; qq++) {
        int f  = qq * 256 + t;
        int i  = f >> 4;
        int j0 = (f & 15) * 4;
        float e = er[i];
        f32x4 o = {e * ec[j0], e * ec[j0 + 1], e * ec[j0 + 2], e * ec[j0 + 3]};
        __builtin_nontemporal_store(o, orow + f);
    }
}

// ---------------------------------------------------------------------------
extern "C" void kernel_launch(void* const* d_in, const int* in_sizes, int n_in,
                              void* d_out, int out_size, void* d_ws, size_t ws_size,
                              hipStream_t stream) {
    const float* X       = (const float*)d_in[0];   // [4096,512]
    const float* W       = (const float*)d_in[1];   // [4096,512]
    const int*   decay_p = (const int*)d_in[3];
    const int*   it_p    = (const int*)d_in[4];
    float* out = (float*)d_out;

    // ws: Xh 4MB | Wh 4MB | w2 16KB | xnorm 16KB | gmins 8MB
    _Float16* Xh = (_Float16*)d_ws;
    _Float16* Wh = Xh + (size_t)BATCH * DIMK;
    float*    w2 = (float*)(Wh + (size_t)MN * DIMK);
    float*    xn = w2 + MN;
    _Float16* gmv = (_Float16*)(xn + BATCH);

    convert_kernel<<<2048, 256, 0, stream>>>(X, W, Xh, Wh, w2, xn);
    score_kernel<<<dim3(32, 32), 256, 0, stream>>>(Xh, Wh, w2, gmv);
    epilogue_kernel<<<BATCH, 256, 0, stream>>>(w2, xn, X, W, gmv, decay_p, it_p, out);
}